// Round 5
// baseline (805.727 us; speedup 1.0000x reference)
//
#include <hip/hip_runtime.h>
#include <stdint.h>

#define P 2048
#define R 65536
#define DD 512
#define BT 128
#define NBLK ((P / BT) * (R / BT))   // 8192

typedef __attribute__((ext_vector_type(8))) short short8;
typedef __attribute__((ext_vector_type(4))) float f32x4;

__device__ inline unsigned short f2bf(float f) {
  unsigned int u = __float_as_uint(f);
  u += 0x7fffu + ((u >> 16) & 1u);   // round-to-nearest-even
  return (unsigned short)(u >> 16);
}

// ---- kernel 1: fp32 -> bf16 conversion + fp32 row norms; one wave per row ----
__global__ __launch_bounds__(256) void k_convert(
    const float* __restrict__ pred, const float* __restrict__ cand,
    unsigned short* __restrict__ Abf, unsigned short* __restrict__ Bbf,
    float* __restrict__ nx, float* __restrict__ ny,
    unsigned int* __restrict__ minp, unsigned int* __restrict__ done)
{
  if (blockIdx.x == 0 && threadIdx.x == 0) { *minp = 0x7f800000u; *done = 0u; }
  int gw   = (blockIdx.x * 256 + threadIdx.x) >> 6;  // global wave = row
  int lane = threadIdx.x & 63;
  if (gw >= P + R) return;
  const float* src; unsigned short* dst; float* np;
  if (gw < P) { src = pred + (size_t)gw * DD; dst = Abf + (size_t)gw * DD; np = nx + gw; }
  else { int r = gw - P; src = cand + (size_t)r * DD; dst = Bbf + (size_t)r * DD; np = ny + r; }
  const float4* s4 = ((const float4*)src) + lane * 2;
  float4 v0 = s4[0], v1 = s4[1];
  float ss = v0.x*v0.x + v0.y*v0.y + v0.z*v0.z + v0.w*v0.w
           + v1.x*v1.x + v1.y*v1.y + v1.z*v1.z + v1.w*v1.w;
  union { unsigned short h[8]; uint4 v; } pk;
  pk.h[0]=f2bf(v0.x); pk.h[1]=f2bf(v0.y); pk.h[2]=f2bf(v0.z); pk.h[3]=f2bf(v0.w);
  pk.h[4]=f2bf(v1.x); pk.h[5]=f2bf(v1.y); pk.h[6]=f2bf(v1.z); pk.h[7]=f2bf(v1.w);
  *(uint4*)(dst + (size_t)lane * 8) = pk.v;
  #pragma unroll
  for (int off = 32; off; off >>= 1) ss += __shfl_down(ss, off, 64);
  if (lane == 0) *np = ss;
}

// ---- kernel 2: 128x128 bf16 MFMA tile GEMM (A·B^T), NO LDS STAGING.
// Fragments are loaded straight from global: for 16x16x32 MFMA each lane's
// fragment is 8 contiguous bf16 = one 16B load; one fragment instruction
// touches 16 fully-consumed 64B lines (same line count as an ideal coalesced
// load). No K-loop barriers -> no vmcnt(0) drains; waves run independently,
// latency hidden by TLP + compiler vmcnt(N) pipelining. A (2MB) is L2-resident
// everywhere; B tiles are re-read 16x via L1/L2/L3.
// Grid mapping: R1's (by=id&15 fast) — XCD swizzle measured SLOWER (R3/R4).
__global__ __launch_bounds__(256) void k_gemm_min(
    const unsigned short* __restrict__ Abf, const unsigned short* __restrict__ Bbf,
    const float* __restrict__ nx, const float* __restrict__ ny,
    unsigned int* __restrict__ minp, unsigned int* __restrict__ done,
    float* __restrict__ out)
{
  __shared__ float wmin[4];

  const int tid  = threadIdx.x;
  const int wave = tid >> 6;
  const int lane = tid & 63;
  const int id = blockIdx.x;
  const int by = id & 15;            // pred tile (fast: 16 adjacent blocks share cand tile)
  const int bx = id >> 4;            // cand tile
  const int rowA0 = by * BT, rowB0 = bx * BT;
  const int wr = wave >> 1, wc = wave & 1;   // wave quadrant in 128x128

  f32x4 zero = {0.f, 0.f, 0.f, 0.f};
  f32x4 acc[4][4];
  #pragma unroll
  for (int i = 0; i < 4; ++i)
    #pragma unroll
    for (int j = 0; j < 4; ++j) acc[i][j] = zero;

  // per-lane fragment base: A[m = lane&15][k = quad*8 + j], row-major stride DD
  const int m = lane & 15, quad = lane >> 4;
  const unsigned short* ap0 = Abf + (size_t)(rowA0 + wr * 64 + m) * DD + quad * 8;
  const unsigned short* bp0 = Bbf + (size_t)(rowB0 + wc * 64 + m) * DD + quad * 8;

  #pragma unroll 2
  for (int k0 = 0; k0 < DD; k0 += 32) {
    short8 af[4], bfr[4];
    #pragma unroll
    for (int i = 0; i < 4; ++i) af[i]  = *(const short8*)(ap0 + i * 16 * DD + k0);
    #pragma unroll
    for (int j = 0; j < 4; ++j) bfr[j] = *(const short8*)(bp0 + j * 16 * DD + k0);
    #pragma unroll
    for (int i = 0; i < 4; ++i)
      #pragma unroll
      for (int j = 0; j < 4; ++j)
        acc[i][j] = __builtin_amdgcn_mfma_f32_16x16x32_bf16(af[i], bfr[j], acc[i][j], 0, 0, 0);
  }

  // epilogue: d^2 = ||x||^2 + ||y||^2 - 2*dot ; C/D layout: col=lane&15, row=quad*4+reg
  const int n16 = lane & 15;
  float lmin = 3.4e38f;
  #pragma unroll
  for (int i = 0; i < 4; ++i) {
    const int mbase = rowA0 + wr * 64 + i * 16 + quad * 4;
    float4 nxv = *(const float4*)(nx + mbase);
    #pragma unroll
    for (int j = 0; j < 4; ++j) {
      const int n = rowB0 + wc * 64 + j * 16 + n16;
      const float nyv = ny[n];
      f32x4 a = acc[i][j];
      lmin = fminf(lmin, nxv.x + nyv - 2.0f * a[0]);
      lmin = fminf(lmin, nxv.y + nyv - 2.0f * a[1]);
      lmin = fminf(lmin, nxv.z + nyv - 2.0f * a[2]);
      lmin = fminf(lmin, nxv.w + nyv - 2.0f * a[3]);
    }
  }
  #pragma unroll
  for (int off = 32; off; off >>= 1) lmin = fminf(lmin, __shfl_down(lmin, off, 64));
  if (lane == 0) wmin[wave] = lmin;
  __syncthreads();
  if (tid == 0) {
    float mn = fminf(fminf(wmin[0], wmin[1]), fminf(wmin[2], wmin[3]));
    atomicMin(minp, __float_as_uint(fmaxf(mn, 0.0f)));
    __threadfence();
    unsigned int old = atomicAdd(done, 1u);
    if (old == (unsigned int)(NBLK - 1)) {
      // min(cur, +inf) == cur: reads the final global min without changing it
      unsigned int bits = atomicMin(minp, 0x7f800000u);
      out[0] = sqrtf(__uint_as_float(bits));
    }
  }
}

// ---- fallback (only if ws too small): exact fp32 brute force ----
__global__ __launch_bounds__(64) void k_initmin(unsigned int* minp) {
  if (threadIdx.x == 0) *minp = 0x7f800000u;
}

__global__ __launch_bounds__(256) void k_brute(
    const float* __restrict__ pred, const float* __restrict__ cand,
    unsigned int* __restrict__ minp)
{
  __shared__ float yrow[DD];
  __shared__ float wm[4];
  const int c = blockIdx.x;
  for (int i = threadIdx.x; i < DD; i += 256) yrow[i] = cand[(size_t)c * DD + i];
  __syncthreads();
  float lmin = 3.4e38f;
  for (int p = threadIdx.x; p < P; p += 256) {
    const float* xp = pred + (size_t)p * DD;
    float s = 0.f;
    for (int k = 0; k < DD; ++k) { float d = xp[k] - yrow[k]; s = fmaf(d, d, s); }
    lmin = fminf(lmin, s);
  }
  #pragma unroll
  for (int off = 32; off; off >>= 1) lmin = fminf(lmin, __shfl_down(lmin, off, 64));
  if ((threadIdx.x & 63) == 0) wm[threadIdx.x >> 6] = lmin;
  __syncthreads();
  if (threadIdx.x == 0) {
    float mn = fminf(fminf(wm[0], wm[1]), fminf(wm[2], wm[3]));
    atomicMin(minp, __float_as_uint(fmaxf(mn, 0.0f)));
  }
}

__global__ __launch_bounds__(64) void k_finalize(const unsigned int* minp, float* out) {
  if (threadIdx.x == 0) out[0] = sqrtf(__uint_as_float(*minp));
}

extern "C" void kernel_launch(void* const* d_in, const int* in_sizes, int n_in,
                              void* d_out, int out_size, void* d_ws, size_t ws_size,
                              hipStream_t stream) {
  const float* pred = (const float*)d_in[0];
  const float* cand = (const float*)d_in[1];
  float* out = (float*)d_out;

  // ws layout: u32[0]=min-bits, u32[32]=done-counter (separate 128B line),
  // +64 floats: nx[2048] | ny[65536] | Abf bf16[2048*512] | Bbf bf16[65536*512]
  unsigned int* minp = (unsigned int*)d_ws;
  unsigned int* done = ((unsigned int*)d_ws) + 32;
  float* wsf = (float*)d_ws;
  float* nx = wsf + 64;
  float* ny = nx + P;
  unsigned short* Abf = (unsigned short*)(ny + R);
  unsigned short* Bbf = Abf + (size_t)P * DD;
  const size_t need = (size_t)(64 + P + R) * 4 + ((size_t)P * DD + (size_t)R * DD) * 2;

  if (ws_size >= need) {
    const int rows = P + R;                 // 67584 rows, 4 waves/block
    k_convert<<<rows / 4, 256, 0, stream>>>(pred, cand, Abf, Bbf, nx, ny, minp, done);
    k_gemm_min<<<NBLK, 256, 0, stream>>>(Abf, Bbf, nx, ny, minp, done, out);
  } else {
    k_initmin<<<1, 64, 0, stream>>>(minp);
    k_brute<<<R, 256, 0, stream>>>(pred, cand, minp);
    k_finalize<<<1, 64, 0, stream>>>(minp, out);
  }
}

// Round 6
// 436.081 us; speedup vs baseline: 1.8477x; 1.8477x over previous
//
#include <hip/hip_runtime.h>
#include <stdint.h>

#define P 2048
#define R 65536
#define DD 512
#define BTW 64                     // per-wave output tile (64x64)
#define NSUB ((P / BTW) * (R / BTW))   // 32 x 1024 = 32768 wave-jobs
#define NSLOT 128

typedef __attribute__((ext_vector_type(8))) short short8;
typedef __attribute__((ext_vector_type(4))) float f32x4;

__device__ inline unsigned short f2bf(float f) {
  unsigned int u = __float_as_uint(f);
  u += 0x7fffu + ((u >> 16) & 1u);   // round-to-nearest-even
  return (unsigned short)(u >> 16);
}

__device__ inline void gload_lds16(const void* g, void* l) {
  __builtin_amdgcn_global_load_lds(
      (const __attribute__((address_space(1))) unsigned int*)g,
      (__attribute__((address_space(3))) unsigned int*)l,
      16, 0, 0);
}

// ---- kernel 1: fp32 -> bf16 conversion + fp32 row norms; one wave per row ----
__global__ __launch_bounds__(256) void k_convert(
    const float* __restrict__ pred, const float* __restrict__ cand,
    unsigned short* __restrict__ Abf, unsigned short* __restrict__ Bbf,
    float* __restrict__ nx, float* __restrict__ ny,
    unsigned int* __restrict__ slots)
{
  if (blockIdx.x == 0 && threadIdx.x < NSLOT) slots[threadIdx.x] = 0x7f800000u; // +inf
  int gw   = (blockIdx.x * 256 + threadIdx.x) >> 6;  // global wave = row
  int lane = threadIdx.x & 63;
  if (gw >= P + R) return;
  const float* src; unsigned short* dst; float* np;
  if (gw < P) { src = pred + (size_t)gw * DD; dst = Abf + (size_t)gw * DD; np = nx + gw; }
  else { int r = gw - P; src = cand + (size_t)r * DD; dst = Bbf + (size_t)r * DD; np = ny + r; }
  const float4* s4 = ((const float4*)src) + lane * 2;
  float4 v0 = s4[0], v1 = s4[1];
  float ss = v0.x*v0.x + v0.y*v0.y + v0.z*v0.z + v0.w*v0.w
           + v1.x*v1.x + v1.y*v1.y + v1.z*v1.z + v1.w*v1.w;
  union { unsigned short h[8]; uint4 v; } pk;
  pk.h[0]=f2bf(v0.x); pk.h[1]=f2bf(v0.y); pk.h[2]=f2bf(v0.z); pk.h[3]=f2bf(v0.w);
  pk.h[4]=f2bf(v1.x); pk.h[5]=f2bf(v1.y); pk.h[6]=f2bf(v1.z); pk.h[7]=f2bf(v1.w);
  *(uint4*)(dst + (size_t)lane * 8) = pk.v;
  #pragma unroll
  for (int off = 32; off; off >>= 1) ss += __shfl_down(ss, off, 64);
  if (lane == 0) *np = ss;
}

// ---- kernel 2: barrier-free per-wave 64x64 MFMA tiles.
// Each wave owns a PRIVATE 8KB LDS region (A 64x32 bf16 + B 64x32), staged via
// global_load_lds. No __syncthreads in the K-loop: per-wave s_waitcnt only.
// Pipeline per iter: vmcnt(0) [tile landed] -> 8x ds_read_b128 frags ->
// lgkmcnt(0) [frags in VGPRs] -> issue NEXT tile's loads into same buffer
// [overlaps MFMAs] -> 16x MFMA. XOR chunk swizzle (R4-verified, conflicts=0):
// stored_chunk = chunk ^ ((row>>1)&3), applied on the global source address.
// Grid mapping: R1's (by fast) — XCD-concentration measured SLOWER (R3/R4).
__global__ __launch_bounds__(128, 4) void k_gemm_min(
    const unsigned short* __restrict__ Abf, const unsigned short* __restrict__ Bbf,
    const float* __restrict__ nx, const float* __restrict__ ny,
    unsigned int* __restrict__ slots)
{
  __shared__ __align__(16) unsigned short S[2][4096];   // 8KB per wave
  const int wave = threadIdx.x >> 6;
  const int lane = threadIdx.x & 63;
  unsigned short* As = &S[wave][0];      // 64 rows x 32 shorts
  unsigned short* Bs = &S[wave][2048];

  const int gsub = blockIdx.x * 2 + wave;
  const int by = gsub & 31;            // pred subtile fast: 32 adjacent jobs share B tile
  const int bx = gsub >> 5;            // cand subtile
  const int rowA0 = by * BTW, rowB0 = bx * BTW;

  f32x4 zero = {0.f, 0.f, 0.f, 0.f};
  f32x4 acc[4][4];
  #pragma unroll
  for (int i = 0; i < 4; ++i)
    #pragma unroll
    for (int j = 0; j < 4; ++j) acc[i][j] = zero;

  // staging: 4 instrs per operand; instr t covers rows 16t..16t+15.
  // lane L: row 16t+(L>>2), stored chunk L&3, source data chunk (L&3)^((L>>3)&3).
  const int cswz = (lane & 3) ^ ((lane >> 3) & 3);
  const unsigned short* gA[4]; const unsigned short* gB[4];
  #pragma unroll
  for (int t = 0; t < 4; ++t) {
    const int rr = t * 16 + (lane >> 2);
    gA[t] = Abf + (size_t)(rowA0 + rr) * DD + cswz * 8;
    gB[t] = Bbf + (size_t)(rowB0 + rr) * DD + cswz * 8;
  }

  // fragment read: A frag i at rows i*16+m, data chunk quad, stored quad^((m>>1)&3)
  const int m = lane & 15, quad = lane >> 4;
  const int sw = (quad ^ ((m >> 1) & 3)) * 8;
  const unsigned short* ap = As + m * 32 + sw;
  const unsigned short* bp = Bs + m * 32 + sw;

  // prologue: stage tile k0=0
  #pragma unroll
  for (int t = 0; t < 4; ++t) {
    gload_lds16(gA[t], As + t * 512);
    gload_lds16(gB[t], Bs + t * 512);
  }

  for (int k0 = 0; k0 < DD; k0 += 32) {
    __builtin_amdgcn_s_waitcnt(0x0F70);   // vmcnt(0): this iter's DMA landed
    short8 af[4], bfv[4];
    #pragma unroll
    for (int i = 0; i < 4; ++i) af[i]  = *(const short8*)(ap + i * 512);
    #pragma unroll
    for (int j = 0; j < 4; ++j) bfv[j] = *(const short8*)(bp + j * 512);
    __builtin_amdgcn_s_waitcnt(0xC07F);   // lgkmcnt(0): frags safely in VGPRs
    if (k0 + 32 < DD) {                   // prefetch next tile into SAME buffer
      #pragma unroll
      for (int t = 0; t < 4; ++t) {
        gload_lds16(gA[t] + k0 + 32, As + t * 512);
        gload_lds16(gB[t] + k0 + 32, Bs + t * 512);
      }
    }
    #pragma unroll
    for (int i = 0; i < 4; ++i)
      #pragma unroll
      for (int j = 0; j < 4; ++j)
        acc[i][j] = __builtin_amdgcn_mfma_f32_16x16x32_bf16(af[i], bfv[j], acc[i][j], 0, 0, 0);
  }

  // epilogue: d^2 = ||x||^2 + ||y||^2 - 2*dot ; C/D: col=lane&15, row=quad*4+reg
  const int n16 = lane & 15;
  float lmin = 3.4e38f;
  #pragma unroll
  for (int i = 0; i < 4; ++i) {
    const int mbase = rowA0 + i * 16 + quad * 4;
    float4 nxv = *(const float4*)(nx + mbase);
    #pragma unroll
    for (int j = 0; j < 4; ++j) {
      const int n = rowB0 + j * 16 + n16;
      const float nyv = ny[n];
      f32x4 a = acc[i][j];
      lmin = fminf(lmin, nxv.x + nyv - 2.0f * a[0]);
      lmin = fminf(lmin, nxv.y + nyv - 2.0f * a[1]);
      lmin = fminf(lmin, nxv.z + nyv - 2.0f * a[2]);
      lmin = fminf(lmin, nxv.w + nyv - 2.0f * a[3]);
    }
  }
  #pragma unroll
  for (int off = 32; off; off >>= 1) lmin = fminf(lmin, __shfl_down(lmin, off, 64));
  if (lane == 0)
    atomicMin(slots + (gsub & (NSLOT - 1)), __float_as_uint(fmaxf(lmin, 0.0f)));
}

// ---- final: reduce 128 slots, sqrt ----
__global__ __launch_bounds__(64) void k_final(const unsigned int* __restrict__ slots,
                                              float* __restrict__ out) {
  const int lane = threadIdx.x;
  float v = fminf(__uint_as_float(slots[lane]), __uint_as_float(slots[lane + 64]));
  #pragma unroll
  for (int off = 32; off; off >>= 1) v = fminf(v, __shfl_down(v, off, 64));
  if (lane == 0) out[0] = sqrtf(v);
}

// ---- fallback (only if ws too small): exact fp32 brute force ----
__global__ __launch_bounds__(128) void k_initmin(unsigned int* slots) {
  if (threadIdx.x < NSLOT) slots[threadIdx.x] = 0x7f800000u;
}

__global__ __launch_bounds__(256) void k_brute(
    const float* __restrict__ pred, const float* __restrict__ cand,
    unsigned int* __restrict__ slots)
{
  __shared__ float yrow[DD];
  __shared__ float wm[4];
  const int c = blockIdx.x;
  for (int i = threadIdx.x; i < DD; i += 256) yrow[i] = cand[(size_t)c * DD + i];
  __syncthreads();
  float lmin = 3.4e38f;
  for (int p = threadIdx.x; p < P; p += 256) {
    const float* xp = pred + (size_t)p * DD;
    float s = 0.f;
    for (int k = 0; k < DD; ++k) { float d = xp[k] - yrow[k]; s = fmaf(d, d, s); }
    lmin = fminf(lmin, s);
  }
  #pragma unroll
  for (int off = 32; off; off >>= 1) lmin = fminf(lmin, __shfl_down(lmin, off, 64));
  if ((threadIdx.x & 63) == 0) wm[threadIdx.x >> 6] = lmin;
  __syncthreads();
  if (threadIdx.x == 0) {
    float mn = fminf(fminf(wm[0], wm[1]), fminf(wm[2], wm[3]));
    atomicMin(slots + (c & (NSLOT - 1)), __float_as_uint(fmaxf(mn, 0.0f)));
  }
}

extern "C" void kernel_launch(void* const* d_in, const int* in_sizes, int n_in,
                              void* d_out, int out_size, void* d_ws, size_t ws_size,
                              hipStream_t stream) {
  const float* pred = (const float*)d_in[0];
  const float* cand = (const float*)d_in[1];
  float* out = (float*)d_out;

  // ws layout: u32 slots[128] | nx[2048] f32 | ny[65536] f32 | Abf bf16 | Bbf bf16
  unsigned int* slots = (unsigned int*)d_ws;
  float* nx = (float*)d_ws + NSLOT;
  float* ny = nx + P;
  unsigned short* Abf = (unsigned short*)(ny + R);
  unsigned short* Bbf = Abf + (size_t)P * DD;
  const size_t need = (size_t)(NSLOT + P + R) * 4 + ((size_t)P * DD + (size_t)R * DD) * 2;

  if (ws_size >= need) {
    const int rows = P + R;                 // 67584 rows, 4 waves/block
    k_convert<<<rows / 4, 256, 0, stream>>>(pred, cand, Abf, Bbf, nx, ny, slots);
    k_gemm_min<<<NSUB / 2, 128, 0, stream>>>(Abf, Bbf, nx, ny, slots);
  } else {
    k_initmin<<<1, 128, 0, stream>>>(slots);
    k_brute<<<R, 256, 0, stream>>>(pred, cand, slots);
  }
  k_final<<<1, 64, 0, stream>>>(slots, out);
}